// Round 1
// 871.751 us; speedup vs baseline: 1.0592x; 1.0592x over previous
//
#include <hip/hip_runtime.h>

#define B_  32
#define L_  2048
#define D_  1024
#define NW_ 409
#define W_  5
#define T_  11
#define H_  8
#define HD_ 128
#define MQ  (B_*NW_)   // 13088
#define MQP 13184      // 103*128 (padded M for q GEMM)

typedef __attribute__((ext_vector_type(16))) float f32x16;
typedef __attribute__((ext_vector_type(8))) __bf16 bf16x8;

__device__ __forceinline__ float b2f(unsigned short u) {
  union { unsigned int i; float f; } x; x.i = ((unsigned int)u) << 16; return x.f;
}
__device__ __forceinline__ unsigned short f2b(float f) {
  union { float f; unsigned int i; } x; x.f = f;
  unsigned int r = (x.i + 0x7FFFu + ((x.i >> 16) & 1u)) >> 16;
  return (unsigned short)r;
}
__device__ __forceinline__ float2 bf2x(unsigned int u) {
  union { unsigned int i; float f; } lo, hi;
  lo.i = u << 16; hi.i = u & 0xffff0000u;
  return make_float2(lo.f, hi.f);
}

__device__ __forceinline__ void async_copy16(const void* g, void* l) {
  __builtin_amdgcn_global_load_lds(
      (const __attribute__((address_space(1))) void*)g,
      (__attribute__((address_space(3))) void*)l, 16, 0, 0);
}

// ---------------- plain fp32 -> bf16 convert (weights + full x), grid-stride ----
__global__ void cvt_kernel(const float* __restrict__ in,
                           unsigned short* __restrict__ out, int n4) {
  int stride = gridDim.x * 256;
  for (int i = blockIdx.x * 256 + threadIdx.x; i < n4; i += stride) {
    float4 v = ((const float4*)in)[i];
    ushort4 o;
    o.x = f2b(v.x); o.y = f2b(v.y); o.z = f2b(v.z); o.w = f2b(v.w);
    ((ushort4*)out)[i] = o;
  }
}

// ---------------- fused head weights, split-K ----------------
// Wcp[eb][d] = sum over e in [eb*64, eb*64+64) of ow[c,e]*opw[e,dd]
__global__ void wc_part_kernel(const float* __restrict__ ow, const float* __restrict__ opw,
                               float* __restrict__ Wcp) {
  int eb = blockIdx.x >> 3, seg = blockIdx.x & 7;   // 16 x 8 blocks
  int d = seg * 256 + threadIdx.x;                  // 0..2047
  int c = d >> 10, dd = d & 1023;
  float acc = 0.f;
  int e0 = eb * 64;
#pragma unroll 8
  for (int e = e0; e < e0 + 64; e++) acc += ow[c * D_ + e] * opw[e * D_ + dd];
  Wcp[eb * 2048 + d] = acc;
}
__global__ void wc_reduce_kernel(const float* __restrict__ Wcp,
                                 const float* __restrict__ ow, const float* __restrict__ opb,
                                 const float* __restrict__ ob,
                                 float* __restrict__ Wc, float* __restrict__ bc) {
  int d = blockIdx.x * 256 + threadIdx.x;
  float s = 0.f;
#pragma unroll
  for (int eb = 0; eb < 16; eb++) s += Wcp[eb * 2048 + d];
  Wc[d] = s;
  if (blockIdx.x == 0 && threadIdx.x < 128) {
    int c = threadIdx.x >> 6, lane = threadIdx.x & 63;
    float p = 0.f;
#pragma unroll
    for (int j = 0; j < 16; j++) p += ow[c * D_ + lane + 64 * j] * opb[lane + 64 * j];
#pragma unroll
    for (int off = 32; off > 0; off >>= 1) p += __shfl_down(p, off);
    if (lane == 0) bc[c] = p + ob[c];
  }
}

// ---------------- NT GEMM, bf16 A, BK=64, 32x32x16 MFMA ----------------------
// C[M,N] = A[M,K] @ Bw[N,K]^T (+bias[N]); 128x128 tile, 4 waves 2x2, wave does
// 2x2 32x32 tiles. LDS slot c holds (r=c>>3, kc=((c&7)-r)&7); read quad
// (c8+rb)&7 cycles with rb -> conflict-free.
// GATHER: A-row rg maps to x-row b*L + W*n + W (query-center gather fused in);
// pad rows (rg>=MQ) clamp to row 0, their C output is never read.
// XCD swizzle: hardware block h dispatches to XCD h%8; remap so each XCD owns
// a contiguous chunk of logical tiles (x fastest -> 16 col-tiles of one
// row-group are consecutive on one XCD -> A row-group stays in that L2).
template<bool GATHER>
__global__ __launch_bounds__(256)
void gemm_bt_kernel(const unsigned short* __restrict__ A,
                    const unsigned short* __restrict__ Bw,
                    unsigned short* __restrict__ C,
                    const float* __restrict__ bias,
                    int N, int K) {
  __shared__ __align__(16) unsigned short sA[128 * 64];
  __shared__ __align__(16) unsigned short sB[128 * 64];
  const int h = blockIdx.y * gridDim.x + blockIdx.x;
  const int chunk = (gridDim.x * gridDim.y) >> 3;   // grid total % 8 == 0
  const int lg = (h & 7) * chunk + (h >> 3);
  const int bx = lg % gridDim.x, by = lg / gridDim.x;
  const int tid = threadIdx.x;
  const int row0 = by * 128;
  const int col0 = bx * 128;
  const int wave = tid >> 6, lane = tid & 63;
  const int wm = wave & 1, wn = wave >> 1;
  const int l31 = lane & 31, lh = lane >> 5;

  // ---- staging coords (each: 1024 16B chunks) ----
  const unsigned short* Asrc[4];
  const unsigned short* Bsrc[4];
#pragma unroll
  for (int u = 0; u < 4; u++) {
    int c = tid + 256 * u;
    int r = c >> 3, kc = ((c & 7) - r) & 7;
    Bsrc[u] = Bw + (size_t)(col0 + r) * K + kc * 8;
    size_t arow;
    if constexpr (GATHER) {
      int mm = row0 + r;
      if (mm >= MQ) mm = 0;                 // pad rows: any valid src
      int b = mm / NW_, n = mm - b * NW_;
      arow = (size_t)b * L_ + (size_t)(W_ * n + W_);
    } else {
      arow = (size_t)(row0 + r);
    }
    Asrc[u] = A + arow * K + kc * 8;
  }

  // ---- fragment read offsets (in shorts) ----
  int offA[4][2], offB[4][2];
#pragma unroll
  for (int kc = 0; kc < 4; kc++) {
    int c8 = kc * 2 + lh;
#pragma unroll
    for (int i = 0; i < 2; i++) {
      int rb = wn * 64 + i * 32 + l31;
      offB[kc][i] = (rb * 8 + ((c8 + rb) & 7)) * 8;
      int ra = wm * 64 + i * 32 + l31;
      offA[kc][i] = (ra * 8 + ((c8 + ra) & 7)) * 8;
    }
  }

  f32x16 acc[2][2];
#pragma unroll
  for (int i = 0; i < 2; i++)
#pragma unroll
    for (int j = 0; j < 2; j++) acc[i][j] = (f32x16)0.0f;

  for (int kt = 0; kt < K; kt += 64) {
#pragma unroll
    for (int u = 0; u < 4; u++)
      async_copy16(Asrc[u] + kt, &sA[(tid + 256 * u) * 8]);
#pragma unroll
    for (int u = 0; u < 4; u++)
      async_copy16(Bsrc[u] + kt, &sB[(tid + 256 * u) * 8]);
    __syncthreads();
#pragma unroll
    for (int kc = 0; kc < 4; kc++) {
      bf16x8 a0 = *(const bf16x8*)&sA[offA[kc][0]];
      bf16x8 a1 = *(const bf16x8*)&sA[offA[kc][1]];
      bf16x8 b0 = *(const bf16x8*)&sB[offB[kc][0]];
      bf16x8 b1 = *(const bf16x8*)&sB[offB[kc][1]];
      acc[0][0] = __builtin_amdgcn_mfma_f32_32x32x16_bf16(a0, b0, acc[0][0], 0, 0, 0);
      acc[0][1] = __builtin_amdgcn_mfma_f32_32x32x16_bf16(a0, b1, acc[0][1], 0, 0, 0);
      acc[1][0] = __builtin_amdgcn_mfma_f32_32x32x16_bf16(a1, b0, acc[1][0], 0, 0, 0);
      acc[1][1] = __builtin_amdgcn_mfma_f32_32x32x16_bf16(a1, b1, acc[1][1], 0, 0, 0);
    }
    __syncthreads();
  }

  // C/D frag (m74/m101): col=lane&31, row=(reg&3)+8*(reg>>2)+4*(lane>>5)
#pragma unroll
  for (int i = 0; i < 2; i++) {
#pragma unroll
    for (int j = 0; j < 2; j++) {
      int gc = col0 + wn * 64 + j * 32 + l31;
      float bv = bias ? bias[gc] : 0.0f;
#pragma unroll
      for (int r = 0; r < 16; r++) {
        int gr = row0 + wm * 64 + i * 32 + (r & 3) + 8 * (r >> 2) + 4 * lh;
        C[(size_t)gr * N + gc] = f2b(acc[i][j][r] + bv);
      }
    }
  }
}

// ---------------- windowed attention + fused classifier head ----------------
// XCD-contiguity swizzle: blocks dispatch round-robin across 8 XCDs; map so
// XCD k owns contiguous windows [k*1636,(k+1)*1636) -> 2.2x KV overlap hits L2.
__global__ __launch_bounds__(256)
void attn_kernel(const unsigned short* __restrict__ q,
                 const unsigned short* __restrict__ kv,
                 const float* __restrict__ Wc, const float* __restrict__ bc,
                 float* __restrict__ out) {
  __shared__ unsigned short sQ[D_];
  __shared__ float sAttn[H_ * T_];
  __shared__ float sRed[8];
  const int blk = blockIdx.x;
  const int m = (blk >> 3) + (blk & 7) * 1636;   // 13088 = 8*1636
  const int b = m / NW_, n = m - b * NW_;
  const int tid = threadIdx.x;
  const size_t rowbase = (size_t)b * L_ * 2048;

  if (tid < 128)
    ((uint4*)sQ)[tid] = ((const uint4*)(q + (size_t)m * D_))[tid];
  __syncthreads();

  // scores: 16 lanes per (h,t); lane reads 8 bf16 of K (256B contiguous/pair)
  {
    const int s = tid & 15, p0 = tid >> 4;
#pragma unroll
    for (int r = 0; r < 6; r++) {
      int pair = r * 16 + p0;           // 0..95, 88 real
      float sc = 0.f;
      if (pair < H_ * T_) {
        int h = pair / T_, t = pair - h * T_;
        int pos = W_ * n + t;
        if (pos < L_) {
          uint4 k4 = *(const uint4*)(kv + rowbase + (size_t)pos * 2048 + h * HD_ + s * 8);
          uint4 q4 = *(const uint4*)(sQ + h * HD_ + s * 8);
          float2 a0 = bf2x(q4.x), b0 = bf2x(k4.x);
          float2 a1 = bf2x(q4.y), b1 = bf2x(k4.y);
          float2 a2 = bf2x(q4.z), b2 = bf2x(k4.z);
          float2 a3 = bf2x(q4.w), b3 = bf2x(k4.w);
          sc = a0.x * b0.x + a0.y * b0.y + a1.x * b1.x + a1.y * b1.y
             + a2.x * b2.x + a2.y * b2.y + a3.x * b3.x + a3.y * b3.y;
        }
      }
      sc += __shfl_down(sc, 8);
      sc += __shfl_down(sc, 4);
      sc += __shfl_down(sc, 2);
      sc += __shfl_down(sc, 1);
      if (pair < H_ * T_ && s == 0)
        sAttn[pair] = sc * 0.08838834764831845f;  // 1/sqrt(128)
    }
  }
  __syncthreads();

  if (tid < H_) {
    float sv[T_];
    float mx = -1e30f;
    for (int t = 0; t < T_; t++) { sv[t] = sAttn[tid * T_ + t]; mx = fmaxf(mx, sv[t]); }
    float sum = 0.f;
    for (int t = 0; t < T_; t++) { sv[t] = expf(sv[t] - mx); sum += sv[t]; }
    float inv = 1.f / sum;
    for (int t = 0; t < T_; t++) sAttn[tid * T_ + t] = sv[t] * inv;
  }
  __syncthreads();

  // o: thread owns 4 contiguous d; V read coalesced; then fused head dot
  {
    int d4 = tid * 4;
    int h = tid >> 5;
    float a0 = 0.f, a1 = 0.f, a2 = 0.f, a3 = 0.f;
#pragma unroll
    for (int t = 0; t < T_; t++) {
      int pos = W_ * n + t;
      if (pos < L_) {
        float w = sAttn[h * T_ + t];
        ushort4 v = *(const ushort4*)(kv + rowbase + (size_t)pos * 2048 + 1024 + d4);
        a0 += w * b2f(v.x); a1 += w * b2f(v.y);
        a2 += w * b2f(v.z); a3 += w * b2f(v.w);
      }
    }
    float4 w0 = ((const float4*)Wc)[tid];
    float4 w1 = ((const float4*)Wc)[256 + tid];
    float p0 = a0 * w0.x + a1 * w0.y + a2 * w0.z + a3 * w0.w;
    float p1 = a0 * w1.x + a1 * w1.y + a2 * w1.z + a3 * w1.w;
#pragma unroll
    for (int off = 32; off > 0; off >>= 1) {
      p0 += __shfl_down(p0, off);
      p1 += __shfl_down(p1, off);
    }
    const int wv = tid >> 6, lane = tid & 63;
    if (lane == 0) { sRed[wv] = p0; sRed[4 + wv] = p1; }
  }
  __syncthreads();

  if (tid == 0) {
    float s0 = sRed[0] + sRed[1] + sRed[2] + sRed[3] + bc[0];
    float s1 = sRed[4] + sRed[5] + sRed[6] + sRed[7] + bc[1];
    float mx = fmaxf(s0, s1);
    float lse = mx + logf(expf(s0 - mx) + expf(s1 - mx));
    size_t row = (size_t)b * L_ + (size_t)(W_ * n);
    out[row * 2 + 0] = s0 - lse;
    out[row * 2 + 1] = s1 - lse;
  }
}

// ---------------- fill output with log(0.5) ----------------
__global__ void fill_kernel(float* __restrict__ out) {
  int i = blockIdx.x * 256 + threadIdx.x;
  out[i] = -0.69314718055994531f;
}

extern "C" void kernel_launch(void* const* d_in, const int* in_sizes, int n_in,
                              void* d_out, int out_size, void* d_ws, size_t ws_size,
                              hipStream_t stream) {
  const float* x          = (const float*)d_in[0];
  const float* in_proj_w  = (const float*)d_in[1];
  const float* in_proj_b  = (const float*)d_in[2];
  const float* out_proj_w = (const float*)d_in[3];
  const float* out_proj_b = (const float*)d_in[4];
  const float* out_w      = (const float*)d_in[5];
  const float* out_b      = (const float*)d_in[6];
  float* out = (float*)d_out;

  // workspace (~432 MB):
  //   [0, 32MB)    qout (MQP x 1024 bf16)
  //   [32MB)       in_proj_w bf16 (wq|wk|wv)  (6.3 MB)
  //   [40MB)       Wc (2x1024 f32), bc, Wcp (16x2048 f32)
  //   [48MB)       xb = x bf16, (B*L) x 1024  (128 MB)
  //   [176MB)      kv = K|V bf16, (B*L) x 2048 (256 MB)
  char* ws = (char*)d_ws;
  unsigned short* qout = (unsigned short*)(ws);
  unsigned short* win  = (unsigned short*)(ws + 33554432);
  float*          Wc   = (float*)(ws + 41943040);
  float*          bc   = (float*)(ws + 41951232);
  float*          Wcp  = (float*)(ws + 41959424);
  unsigned short* xb   = (unsigned short*)(ws + 50331648);
  unsigned short* kvb  = (unsigned short*)(ws + 184549376);

  cvt_kernel<<<3072, 256, 0, stream>>>(in_proj_w, win, 786432);
  cvt_kernel<<<8192, 256, 0, stream>>>(x, xb, 16777216);   // full x -> bf16
  wc_part_kernel<<<128, 256, 0, stream>>>(out_w, out_proj_w, Wcp);
  wc_reduce_kernel<<<8, 256, 0, stream>>>(Wcp, out_w, out_proj_b, out_b, Wc, bc);

  dim3 gkv(16, 512);  // N=2048 (K|V) x M=65536; A = bf16 xb
  gemm_bt_kernel<false><<<gkv, 256, 0, stream>>>(xb, win + 1048576, kvb,
                                                 in_proj_b + 1024, 2048, 1024);
  dim3 gq(8, 103);    // M=13184, N=1024; A = bf16 xb with fused center-gather
  gemm_bt_kernel<true><<<gq, 256, 0, stream>>>(xb, win, qout, in_proj_b, 1024, 1024);

  fill_kernel<<<512, 256, 0, stream>>>(out);  // exactly out_size=131072 floats
  attn_kernel<<<MQ, 256, 0, stream>>>(qout, kvb, Wc, bc, out);
}